// Round 1
// baseline (118.072 us; speedup 1.0000x reference)
//
#include <hip/hip_runtime.h>
#include <hip/hip_bf16.h>

// TripletLoss batch-hard mining, B=8192, D=256.
// Pipeline: normalize->bf16 | MFMA Gram + fused hard mining | reduce | finalize.

constexpr int NB = 8192;   // batch
constexpr int ND = 256;    // dim
constexpr int BI = 128;    // anchors per block
constexpr int BJ = 64;     // j columns per iteration
constexpr int JSPLIT = 8;  // j-range splits (grid.y)
constexpr int JRANGE = NB / JSPLIT;  // 1024
constexpr int NITER = JRANGE / BJ;   // 16

typedef __attribute__((ext_vector_type(8))) short bf16x8;
typedef __attribute__((ext_vector_type(4))) float f32x4;

typedef __attribute__((address_space(3))) unsigned int lds_u32;
typedef __attribute__((address_space(1))) const unsigned int g_u32;

__device__ inline void load_lds16(const unsigned short* g, unsigned short* l) {
    __builtin_amdgcn_global_load_lds((g_u32*)g, (lds_u32*)l, 16, 0, 0);
}

// ---------------- Kernel 1: normalize rows, cast to bf16 ----------------
__global__ __launch_bounds__(256) void norm_kernel(const float* __restrict__ X,
                                                   __hip_bfloat16* __restrict__ Xb) {
    const int row = blockIdx.x;
    const int t = threadIdx.x;
    float v = X[row * ND + t];
    float s = v * v;
    #pragma unroll
    for (int off = 32; off > 0; off >>= 1) s += __shfl_down(s, off, 64);
    __shared__ float wsum[4];
    const int wv = t >> 6, ln = t & 63;
    if (ln == 0) wsum[wv] = s;
    __syncthreads();
    const float tot = wsum[0] + wsum[1] + wsum[2] + wsum[3];
    const float d = fmaxf(sqrtf(tot), 1e-12f);
    Xb[row * ND + t] = __float2bfloat16(v / d);
}

// ---------------- Kernel 2: Gram + hard mining ----------------
// grid (NB/BI, JSPLIT), block 256 (4 waves). Wave w owns anchor rows
// [ib + w*32, +32). A-frags live in registers (K=256 fully). B-tile staged in
// LDS via global_load_lds(16B) with XOR chunk swizzle on the SOURCE address:
//   LDS[j][c] = Global[j][c ^ (j&7)]   (c = 16B chunk index, 32 per row)
// so fragment reads LDS[n][q ^ (n&7)] are 2-way-bank (free) instead of 16-way.
__global__ __launch_bounds__(256, 2) void mine_kernel(
    const unsigned short* __restrict__ Xb, const int* __restrict__ labels,
    float* __restrict__ pos_part, float* __restrict__ neg_part) {
    __shared__ unsigned short Bt[BJ * ND];  // 32 KB, row-major (swizzled chunks)
    __shared__ int Lj[BJ];

    const int tid = threadIdx.x;
    const int w = tid >> 6;
    const int lane = tid & 63;
    const int quad = lane >> 4;
    const int l16 = lane & 15;

    const int ib = blockIdx.x * BI;
    const int jstart = blockIdx.y * JRANGE;

    // A fragments: A[m=lane&15][k = kc*32 + quad*8 + j]
    bf16x8 afrag[2][8];
    int lbla[2][4];
    float posv[2][4], negv[2][4];
    #pragma unroll
    for (int rs = 0; rs < 2; rs++) {
        const int arow = ib + w * 32 + rs * 16 + l16;
        const bf16x8* ap = (const bf16x8*)(Xb + (size_t)arow * ND);
        #pragma unroll
        for (int kc = 0; kc < 8; kc++) afrag[rs][kc] = ap[kc * 4 + quad];
        #pragma unroll
        for (int r = 0; r < 4; r++) {
            const int rrow = ib + w * 32 + rs * 16 + quad * 4 + r;
            lbla[rs][r] = labels[rrow];
            posv[rs][r] = -1e9f;
            negv[rs][r] = 1e9f;
        }
    }

    for (int jt = 0; jt < NITER; jt++) {
        const int jbase = jstart + jt * BJ;
        __syncthreads();  // protect Bt/Lj from overwrite while still read
        // stage: wave w stages 1KB chunks [w*8, w*8+8); each 1KB = 2 rows
        #pragma unroll
        for (int s = 0; s < 8; s++) {
            const int chunk = w * 8 + s;
            const int j = chunk * 2 + (lane >> 5);  // row in tile
            const int c = lane & 31;                // dest 16B chunk in row
            const int cs = c ^ (j & 7);             // swizzled source chunk
            const unsigned short* src = Xb + (size_t)(jbase + j) * ND + cs * 8;
            load_lds16(src, Bt + chunk * 512);
        }
        if (tid < BJ) Lj[tid] = labels[jbase + tid];
        __syncthreads();  // drains vmcnt incl. global_load_lds

        f32x4 acc[2][4];
        #pragma unroll
        for (int rs = 0; rs < 2; rs++)
            #pragma unroll
            for (int nf = 0; nf < 4; nf++) acc[rs][nf] = (f32x4){0.f, 0.f, 0.f, 0.f};

        #pragma unroll
        for (int nf = 0; nf < 4; nf++) {
            const int n = nf * 16 + l16;
            #pragma unroll
            for (int kc = 0; kc < 8; kc++) {
                const int q = kc * 4 + quad;        // global 16B chunk wanted
                const int cidx = q ^ (n & 7);       // swizzled LDS position
                const bf16x8 b = *(const bf16x8*)(Bt + n * ND + cidx * 8);
                acc[0][nf] = __builtin_amdgcn_mfma_f32_16x16x32_bf16(
                    afrag[0][kc], b, acc[0][nf], 0, 0, 0);
                acc[1][nf] = __builtin_amdgcn_mfma_f32_16x16x32_bf16(
                    afrag[1][kc], b, acc[1][nf], 0, 0, 0);
            }
        }

        // epilogue: C/D layout col=lane&15, row=quad*4+reg
        const bool overlap = (ib < jbase + BJ) && (jbase < ib + BI);
        #pragma unroll
        for (int nf = 0; nf < 4; nf++) {
            const int col = jbase + nf * 16 + l16;
            const int lj = Lj[nf * 16 + l16];
            #pragma unroll
            for (int rs = 0; rs < 2; rs++) {
                #pragma unroll
                for (int r = 0; r < 4; r++) {
                    const float dist = fmaxf(1.0f - acc[rs][nf][r], 0.0f);
                    const bool same = (lbla[rs][r] == lj);
                    const int rowg = ib + w * 32 + rs * 16 + quad * 4 + r;
                    const bool isdiag = overlap && (rowg == col);
                    if (same && !isdiag) posv[rs][r] = fmaxf(posv[rs][r], dist);
                    if (!same) negv[rs][r] = fminf(negv[rs][r], dist);
                }
            }
        }
    }

    // reduce across the 16 lanes sharing each row (lane bits 0..3)
    #pragma unroll
    for (int rs = 0; rs < 2; rs++) {
        #pragma unroll
        for (int r = 0; r < 4; r++) {
            float p = posv[rs][r], nn = negv[rs][r];
            #pragma unroll
            for (int m = 1; m <= 8; m <<= 1) {
                p = fmaxf(p, __shfl_xor(p, m, 64));
                nn = fminf(nn, __shfl_xor(nn, m, 64));
            }
            if (l16 == 0) {
                const int rowg = ib + w * 32 + rs * 16 + quad * 4 + r;
                pos_part[blockIdx.y * NB + rowg] = p;
                neg_part[blockIdx.y * NB + rowg] = nn;
            }
        }
    }
}

// ---------------- Kernel 3: combine splits, per-anchor hinge, reduce ----------------
__global__ __launch_bounds__(256) void finish1(const float* __restrict__ pos_part,
                                               const float* __restrict__ neg_part,
                                               float* __restrict__ accum) {
    const int i = blockIdx.x * 256 + threadIdx.x;
    float p = -1e9f, n = 1e9f;
    #pragma unroll
    for (int s = 0; s < JSPLIT; s++) {
        p = fmaxf(p, pos_part[s * NB + i]);
        n = fminf(n, neg_part[s * NB + i]);
    }
    const bool valid = (p > -5e8f) && (n < 5e8f);
    float per = valid ? fmaxf(p - n + 1.0f, 0.0f) : 0.0f;
    float cnt = valid ? 1.0f : 0.0f;
    #pragma unroll
    for (int off = 32; off > 0; off >>= 1) {
        per += __shfl_down(per, off, 64);
        cnt += __shfl_down(cnt, off, 64);
    }
    __shared__ float sp[4], sc[4];
    const int wv = threadIdx.x >> 6, ln = threadIdx.x & 63;
    if (ln == 0) { sp[wv] = per; sc[wv] = cnt; }
    __syncthreads();
    if (threadIdx.x == 0) {
        atomicAdd(&accum[0], sp[0] + sp[1] + sp[2] + sp[3]);
        atomicAdd(&accum[1], sc[0] + sc[1] + sc[2] + sc[3]);
    }
}

__global__ void finish2(const float* __restrict__ accum, float* __restrict__ out) {
    const float s = accum[0], c = accum[1];
    out[0] = (c > 0.0f) ? s / fmaxf(c, 1.0f) : 0.0f;
}

// ---------------- launcher ----------------
extern "C" void kernel_launch(void* const* d_in, const int* in_sizes, int n_in,
                              void* d_out, int out_size, void* d_ws, size_t ws_size,
                              hipStream_t stream) {
    const float* X = (const float*)d_in[0];
    const int* labels = (const int*)d_in[1];
    float* out = (float*)d_out;

    char* ws = (char*)d_ws;
    __hip_bfloat16* Xb = (__hip_bfloat16*)ws;                     // 4 MB
    float* pos_part = (float*)(ws + (size_t)4 * 1024 * 1024);     // 256 KB
    float* neg_part = pos_part + JSPLIT * NB;                     // 256 KB
    float* accum = neg_part + JSPLIT * NB;                        // 8 B

    hipMemsetAsync(accum, 0, 2 * sizeof(float), stream);
    norm_kernel<<<NB, 256, 0, stream>>>(X, Xb);
    mine_kernel<<<dim3(NB / BI, JSPLIT), 256, 0, stream>>>(
        (const unsigned short*)Xb, labels, pos_part, neg_part);
    finish1<<<NB / 256, 256, 0, stream>>>(pos_part, neg_part, accum);
    finish2<<<1, 1, 0, stream>>>(accum, out);
}

// Round 2
// 98.970 us; speedup vs baseline: 1.1930x; 1.1930x over previous
//
#include <hip/hip_runtime.h>
#include <hip/hip_bf16.h>

// TripletLoss batch-hard mining, B=8192, D=256.
// R2: chunk-major bf16 layout + conflict-free lane-sequential LDS reads,
//     M_w=64 rows/wave (A in 128 VGPRs), label-encoded mining key, 3 launches.

constexpr int NB = 8192;
constexpr int ND = 256;
constexpr int BI = 256;               // rows per block (4 waves x 64 rows)
constexpr int BJ = 64;                // cols per iteration
constexpr int JSPLIT = 16;            // grid.y
constexpr int JRANGE = NB / JSPLIT;   // 512
constexpr int NITER = JRANGE / BJ;    // 8
constexpr int NCHUNK = ND / 8;        // 32 16B chunks per row

typedef __attribute__((ext_vector_type(8))) short bf16x8;
typedef __attribute__((ext_vector_type(4))) float f32x4;

typedef __attribute__((address_space(3))) unsigned int lds_u32;
typedef __attribute__((address_space(1))) const unsigned int g_u32;

__device__ inline void load_lds16(const unsigned short* g, unsigned short* l) {
    __builtin_amdgcn_global_load_lds((g_u32*)g, (lds_u32*)l, 16, 0, 0);
}

__device__ inline unsigned short f2bf(float v) {
    __hip_bfloat16 b = __float2bfloat16(v);
    return *reinterpret_cast<unsigned short*>(&b);
}

// ---------------- Kernel 1: normalize rows -> bf16, CHUNK-MAJOR layout ------
// Xbt 16B-unit index = chunk*NB + row  (chunk = k/8). Also zero-inits accum.
__global__ __launch_bounds__(256) void norm_kernel(const float* __restrict__ X,
                                                   unsigned short* __restrict__ Xbt,
                                                   float* accum, int* done) {
    __shared__ float tile[32][260];   // +4 pad breaks phase-2 bank conflicts
    __shared__ float psum[32][8];
    __shared__ float rscale[32];
    const int t = threadIdx.x;
    const int rb = blockIdx.x * 32;
    if (blockIdx.x == 0 && t == 0) { accum[0] = 0.f; accum[1] = 0.f; *done = 0; }
    // coalesced load of 32x256 f32 tile
    #pragma unroll
    for (int k = 0; k < 8; k++) {
        const int f = k * 256 + t;            // float4 index within tile
        const int row = f >> 6, c4 = f & 63;
        const float4 v = *((const float4*)(X + (size_t)(rb + row) * ND) + c4);
        *(float4*)&tile[row][c4 * 4] = v;
    }
    __syncthreads();
    {   // 8 threads per row sum squares
        const int r = t >> 3, e = t & 7;
        float s = 0.f;
        #pragma unroll
        for (int i = 0; i < 32; i++) { const float v = tile[r][e * 32 + i]; s += v * v; }
        psum[r][e] = s;
    }
    __syncthreads();
    if (t < 32) {
        float s = 0.f;
        #pragma unroll
        for (int e = 0; e < 8; e++) s += psum[t][e];
        rscale[t] = 1.0f / fmaxf(sqrtf(s), 1e-12f);
    }
    __syncthreads();
    // chunk-major bf16 store: 32 consecutive threads write 32 rows of one chunk
    #pragma unroll
    for (int j = 0; j < 4; j++) {
        const int idx = j * 256 + t;          // q*32 + r
        const int q = idx >> 5, r = idx & 31;
        const float sc = rscale[r];
        unsigned short tmp[8];
        #pragma unroll
        for (int e = 0; e < 8; e++) tmp[e] = f2bf(tile[r][q * 8 + e] * sc);
        *(bf16x8*)(Xbt + ((size_t)q * NB + rb + r) * 8) = *(bf16x8*)tmp;
    }
}

// ---------------- Kernel 2: Gram + hard mining ------------------------------
// Wave owns 64 rows (4 x 16), K=256 of A in registers. B-tile (64 cols) staged
// in LDS in READ-ORDER: region rg = kc*4+nf holds, at lane L*16B:
//   B[col = nf*16 + (L&15)][kchunk = kc*4 + (L>>4)]
// => every ds_read_b128 is lane-sequential (conflict-free, zero addr VALU).
// Mining key: key = s + 8*min(|lrow-lcol|,1); min(key)=hardest-pos sim,
// max(key)=8+hardest-neg sim. Diagonal (s~1) can never win the pos-min.
__global__ __launch_bounds__(256, 2) void mine_kernel(
    const unsigned short* __restrict__ Xbt, const int* __restrict__ labels,
    float* __restrict__ posP, float* __restrict__ negP) {
    __shared__ unsigned short Bt[32 * 512];   // 32 KB
    __shared__ float Ljf[BJ];

    const int tid = threadIdx.x;
    const int w = tid >> 6;
    const int lane = tid & 63;
    const int quad = lane >> 4;
    const int l16 = lane & 15;

    const int rowbase = blockIdx.x * BI + w * 64;
    const int jstart = blockIdx.y * JRANGE;

    // A fragments: afrag[rs][kc] = 16B of row (rowbase+rs*16+l16), chunk (kc*4+quad)
    bf16x8 afrag[4][8];
    #pragma unroll
    for (int rs = 0; rs < 4; rs++)
        #pragma unroll
        for (int kc = 0; kc < 8; kc++) {
            const size_t u = (size_t)(kc * 4 + quad) * NB + (rowbase + rs * 16 + l16);
            afrag[rs][kc] = *(const bf16x8*)(Xbt + u * 8);
        }

    float flr[4][4];
    float minK[4][4], maxK[4][4];
    #pragma unroll
    for (int rs = 0; rs < 4; rs++)
        #pragma unroll
        for (int r = 0; r < 4; r++) {
            flr[rs][r] = (float)labels[rowbase + rs * 16 + quad * 4 + r];
            minK[rs][r] = 1e30f;
            maxK[rs][r] = -1e30f;
        }

    for (int jt = 0; jt < NITER; jt++) {
        const int jbase = jstart + jt * BJ;
        __syncthreads();
        #pragma unroll
        for (int s = 0; s < 8; s++) {
            const int rg = w * 8 + s;
            const int kc = rg >> 2, nfi = rg & 3;
            const size_t u = (size_t)(kc * 4 + quad) * NB + (jbase + nfi * 16 + l16);
            load_lds16(Xbt + u * 8, Bt + rg * 512);
        }
        if (tid < BJ) Ljf[tid] = (float)labels[jbase + tid];
        __syncthreads();

        #pragma unroll
        for (int nf = 0; nf < 4; nf++) {
            const float flc = Ljf[nf * 16 + l16];
            f32x4 acc[4];
            #pragma unroll
            for (int rs = 0; rs < 4; rs++) acc[rs] = (f32x4){0.f, 0.f, 0.f, 0.f};
            #pragma unroll
            for (int kc = 0; kc < 8; kc++) {
                const bf16x8 b = *(const bf16x8*)(Bt + (kc * 4 + nf) * 512 + lane * 8);
                #pragma unroll
                for (int rs = 0; rs < 4; rs++)
                    acc[rs] = __builtin_amdgcn_mfma_f32_16x16x32_bf16(
                        afrag[rs][kc], b, acc[rs], 0, 0, 0);
            }
            #pragma unroll
            for (int rs = 0; rs < 4; rs++)
                #pragma unroll
                for (int r = 0; r < 4; r++) {
                    const float d = flr[rs][r] - flc;
                    const float uu = fminf(fabsf(d), 1.0f);
                    const float key = fmaf(uu, 8.0f, acc[rs][r]);
                    minK[rs][r] = fminf(minK[rs][r], key);
                    maxK[rs][r] = fmaxf(maxK[rs][r], key);
                }
        }
    }

    // reduce across the 16 lanes (bits 0..3) sharing each row
    #pragma unroll
    for (int rs = 0; rs < 4; rs++)
        #pragma unroll
        for (int r = 0; r < 4; r++) {
            float p = minK[rs][r], n = maxK[rs][r];
            #pragma unroll
            for (int m = 1; m <= 8; m <<= 1) {
                p = fminf(p, __shfl_xor(p, m, 64));
                n = fmaxf(n, __shfl_xor(n, m, 64));
            }
            if (l16 == 0) {
                const int row = rowbase + rs * 16 + quad * 4 + r;
                posP[blockIdx.y * NB + row] = p;
                negP[blockIdx.y * NB + row] = n;
            }
        }
}

// ---------------- Kernel 3: combine splits, hinge, global reduce, finalize --
__global__ __launch_bounds__(256) void finish_kernel(
    const float* __restrict__ posP, const float* __restrict__ negP,
    float* accum, int* done, float* __restrict__ out) {
    const int i = blockIdx.x * 256 + threadIdx.x;
    float p = 1e30f, n = -1e30f;
    #pragma unroll
    for (int s = 0; s < JSPLIT; s++) {
        p = fminf(p, posP[s * NB + i]);
        n = fmaxf(n, negP[s * NB + i]);
    }
    // p < 4: some positive existed; n > 4: some negative existed (key = s+8)
    const bool valid = (p < 4.0f) && (n > 4.0f);
    const float pos_d = fmaxf(1.0f - p, 0.0f);
    const float neg_d = fmaxf(1.0f - (n - 8.0f), 0.0f);
    float per = valid ? fmaxf(pos_d - neg_d + 1.0f, 0.0f) : 0.0f;
    float cnt = valid ? 1.0f : 0.0f;
    #pragma unroll
    for (int off = 32; off > 0; off >>= 1) {
        per += __shfl_down(per, off, 64);
        cnt += __shfl_down(cnt, off, 64);
    }
    __shared__ float sp[4], sc[4];
    const int wv = threadIdx.x >> 6, ln = threadIdx.x & 63;
    if (ln == 0) { sp[wv] = per; sc[wv] = cnt; }
    __syncthreads();
    if (threadIdx.x == 0) {
        atomicAdd(&accum[0], sp[0] + sp[1] + sp[2] + sp[3]);
        atomicAdd(&accum[1], sc[0] + sc[1] + sc[2] + sc[3]);
        __threadfence();
        const int old = atomicAdd(done, 1);
        if (old == (int)gridDim.x - 1) {
            const float s = __hip_atomic_load(&accum[0], __ATOMIC_RELAXED,
                                              __HIP_MEMORY_SCOPE_AGENT);
            const float c = __hip_atomic_load(&accum[1], __ATOMIC_RELAXED,
                                              __HIP_MEMORY_SCOPE_AGENT);
            out[0] = (c > 0.f) ? s / fmaxf(c, 1.f) : 0.f;
        }
    }
}

// ---------------- launcher --------------------------------------------------
extern "C" void kernel_launch(void* const* d_in, const int* in_sizes, int n_in,
                              void* d_out, int out_size, void* d_ws, size_t ws_size,
                              hipStream_t stream) {
    const float* X = (const float*)d_in[0];
    const int* labels = (const int*)d_in[1];
    float* out = (float*)d_out;

    char* ws = (char*)d_ws;
    unsigned short* Xbt = (unsigned short*)ws;                    // 4 MB
    float* posP = (float*)(ws + (size_t)4 * 1024 * 1024);         // 512 KB
    float* negP = posP + JSPLIT * NB;                             // 512 KB
    float* accum = negP + JSPLIT * NB;                            // 8 B
    int* done = (int*)(accum + 2);                                // 4 B

    norm_kernel<<<NB / 32, 256, 0, stream>>>(X, Xbt, accum, done);
    mine_kernel<<<dim3(NB / BI, JSPLIT), 256, 0, stream>>>(
        (const unsigned short*)Xbt, labels, posP, negP);
    finish_kernel<<<NB / 256, 256, 0, stream>>>(posP, negP, accum, done, out);
}